// Round 5
// baseline (441.579 us; speedup 1.0000x reference)
//
#include <hip/hip_runtime.h>
#include <hip/hip_bf16.h>
#include <stdint.h>

#define B_ 8
#define T_ 1024
#define E_ 1024
#define H_ 16
#define D_ 64
#define NREL 2047  // 2T-1

using bf16 = __hip_bfloat16;
typedef __attribute__((ext_vector_type(8))) short bhalf8;   // 8 bf16 = 4 VGPRs
typedef __attribute__((ext_vector_type(4))) float f32x4;

// --- async global->LDS, 16B/lane. LDS dest = wave-uniform base + lane*16. ---
typedef __attribute__((address_space(3))) uint32_t lds32_t;
typedef const __attribute__((address_space(1))) uint32_t glb32_t;
__device__ __forceinline__ void gld_lds16(const bf16* g, bf16* l) {
  __builtin_amdgcn_global_load_lds((glb32_t*)(const void*)g, (lds32_t*)(void*)l, 16, 0, 0);
}

__device__ __forceinline__ bhalf8 cvt8(float4 a, float4 b) {
  bf16 t[8];
  t[0] = __float2bfloat16(a.x); t[1] = __float2bfloat16(a.y);
  t[2] = __float2bfloat16(a.z); t[3] = __float2bfloat16(a.w);
  t[4] = __float2bfloat16(b.x); t[5] = __float2bfloat16(b.y);
  t[6] = __float2bfloat16(b.z); t[7] = __float2bfloat16(b.w);
  return *(const bhalf8*)t;
}

// ---------------------------------------------------------------------------
// fp32 -> bf16 elementwise (weights only; n multiple of 8)
// ---------------------------------------------------------------------------
__global__ __launch_bounds__(256) void cvt_f32_bf16(const float* __restrict__ s,
                                                    bf16* __restrict__ d, int n) {
  const int i = (blockIdx.x * 256 + threadIdx.x) * 8;
  if (i >= n) return;
  *(bhalf8*)(d + i) = cvt8(*(const float4*)(s + i), *(const float4*)(s + i + 4));
}

// ---------------------------------------------------------------------------
// Bias table, pre-scaled by log2(e) for exp2-based softmax.
// db[h][r], r = (q-k)+1023 in [0,2046]
// ---------------------------------------------------------------------------
__global__ void bias_pre(const float* __restrict__ table, const float* __restrict__ offset,
                         float* __restrict__ db) {
  const int idx = blockIdx.x * 256 + threadIdx.x;
  if (idx >= NREL * H_) return;
  const int r = idx >> 4;
  const int h = idx & 15;
  const float bounded = tanhf(offset[0]) * 0.5f;
  float adj = fminf(fmaxf((float)r + bounded, 0.f), 2046.f);
  const int lo = (int)floorf(adj);
  const int hi = (int)ceilf(adj);
  const float wgt = adj - (float)lo;
  const float v = table[lo * H_ + h] * (1.f - wgt) + table[hi * H_ + h] * wgt;
  db[h * NREL + r] = v * 1.44269504088896f;  // * log2(e)
}

// ---------------------------------------------------------------------------
// C = A @ W^T + bias (both operands K-contiguous). 128x128 tile, BK=32.
// A-side -> As (output rows), W-side -> Bs (output cols).
// AF32/WF32: that side is fp32 in global; staged via reg-load + cvt + ds_write.
//            Otherwise bf16 via global_load_lds w=16.
// MODE 0: fp32 out [M,E]; MODE 1: bf16 scatter [B,H,T,D] (rows=(b,t), cols=(h,d));
// MODE 2: bf16 scatter [B,H,D,T] (rows=(h,d)+bias, cols=(b,t)).
// ---------------------------------------------------------------------------
template <int MODE, int AF32, int WF32>
__global__ __launch_bounds__(256) void gemm_bt(const void* __restrict__ A_,
                                               const void* __restrict__ W_,
                                               const float* __restrict__ bias,
                                               void* __restrict__ dst_) {
  __shared__ bf16 As[128 * 32];
  __shared__ bf16 Bs[128 * 32];
  const int tid = threadIdx.x;
  const int lane = tid & 63;
  const int w = tid >> 6;
  const int quad = lane >> 4;
  const int l15 = lane & 15;
  const int m0 = blockIdx.x * 128;
  const int n0 = blockIdx.y * 128;
  const int wm = (w >> 1) * 64;
  const int wn = (w & 1) * 64;

  const f32x4 zero4 = {0.f, 0.f, 0.f, 0.f};
  f32x4 acc[4][4];
#pragma unroll
  for (int i = 0; i < 4; ++i)
#pragma unroll
    for (int j = 0; j < 4; ++j) acc[i][j] = zero4;

  const int srow0 = w * 32 + (lane >> 2);
  const int scol = (lane & 3) * 8;
  const bf16* Ab = (const bf16*)A_ + (size_t)(m0 + srow0) * E_ + scol;
  const float* Af = (const float*)A_ + (size_t)(m0 + srow0) * E_ + scol;
  const bf16* Wb = (const bf16*)W_ + (size_t)(n0 + srow0) * E_ + scol;
  const float* Wf = (const float*)W_ + (size_t)(n0 + srow0) * E_ + scol;
  bf16* As0 = As + w * 1024 + lane * 8;  // == &As[srow0*32 + scol]
  bf16* Bs0 = Bs + w * 1024 + lane * 8;

  for (int kt = 0; kt < 32; ++kt) {
    const int kc = kt * 32;
    float4 ar0, ar1, ar2, ar3, wr0, wr1, wr2, wr3;
    if (AF32) {
      ar0 = *(const float4*)(Af + kc);
      ar1 = *(const float4*)(Af + kc + 4);
      ar2 = *(const float4*)(Af + (size_t)16 * E_ + kc);
      ar3 = *(const float4*)(Af + (size_t)16 * E_ + kc + 4);
    }
    if (WF32) {
      wr0 = *(const float4*)(Wf + kc);
      wr1 = *(const float4*)(Wf + kc + 4);
      wr2 = *(const float4*)(Wf + (size_t)16 * E_ + kc);
      wr3 = *(const float4*)(Wf + (size_t)16 * E_ + kc + 4);
    }
    __syncthreads();  // previous iteration's readers done
    if (AF32) {
      *(bhalf8*)(As + srow0 * 32 + scol) = cvt8(ar0, ar1);
      *(bhalf8*)(As + (srow0 + 16) * 32 + scol) = cvt8(ar2, ar3);
    } else {
      gld_lds16(Ab + kc, As0);
      gld_lds16(Ab + (size_t)16 * E_ + kc, As0 + 512);
    }
    if (WF32) {
      *(bhalf8*)(Bs + srow0 * 32 + scol) = cvt8(wr0, wr1);
      *(bhalf8*)(Bs + (srow0 + 16) * 32 + scol) = cvt8(wr2, wr3);
    } else {
      gld_lds16(Wb + kc, Bs0);
      gld_lds16(Wb + (size_t)16 * E_ + kc, Bs0 + 512);
    }
    __syncthreads();  // drains vmcnt/lgkm: LDS ready

    bhalf8 af[4], bfr[4];
#pragma unroll
    for (int t = 0; t < 4; ++t) {
      af[t] = *(const bhalf8*)(As + (wm + t * 16 + l15) * 32 + quad * 8);
      bfr[t] = *(const bhalf8*)(Bs + (wn + t * 16 + l15) * 32 + quad * 8);
    }
#pragma unroll
    for (int mt = 0; mt < 4; ++mt)
#pragma unroll
      for (int nt = 0; nt < 4; ++nt)
        acc[mt][nt] = __builtin_amdgcn_mfma_f32_16x16x32_bf16(af[mt], bfr[nt], acc[mt][nt], 0, 0, 0);
  }

#pragma unroll
  for (int mt = 0; mt < 4; ++mt) {
    float bi[4];
    if (MODE == 2) {
#pragma unroll
      for (int r = 0; r < 4; ++r) bi[r] = bias[m0 + wm + mt * 16 + quad * 4 + r];
    }
#pragma unroll
    for (int nt = 0; nt < 4; ++nt) {
      const int n = n0 + wn + nt * 16 + l15;
      const float bv = (MODE == 2) ? 0.f : bias[n];
#pragma unroll
      for (int r = 0; r < 4; ++r) {
        const int m = m0 + wm + mt * 16 + quad * 4 + r;  // C row = quad*4+reg
        if (MODE == 1) {
          const float v = acc[mt][nt][r] + bv;
          const int bb = m >> 10, t = m & 1023, hh = n >> 6, d = n & 63;
          ((bf16*)dst_)[(((size_t)bb * H_ + hh) * T_ + t) * D_ + d] = __float2bfloat16(v);
        } else if (MODE == 2) {
          const float v = acc[mt][nt][r] + bi[r];
          const int hh = m >> 6, d = m & 63, bb = n >> 10, t = n & 1023;
          ((bf16*)dst_)[(((size_t)bb * H_ + hh) * D_ + d) * T_ + t] = __float2bfloat16(v);
        } else {
          ((float*)dst_)[(size_t)m * E_ + n] = acc[mt][nt][r] + bv;
        }
      }
    }
  }
}

// ---------------------------------------------------------------------------
// Flash attention, S^T formulation. Per block: 128 q (4 waves x 32), KV tile 64.
// Q,K in [B,H,T,D]; V pre-transposed in [B,H,D,T]. No online max (logits
// provably tiny); l-reduction deferred. Bias read from global (L1-resident).
// S^T = K Q^T  -> C-layout rows = kv (reg index runs along kv!)
// P^T -> LDS Pq[q][kv] via ds_write_b64; PV as O^T = V^T P^T, B-frag b128.
// ---------------------------------------------------------------------------
__global__ __launch_bounds__(256) void attn_kernel(const bf16* __restrict__ Q,
                                                   const bf16* __restrict__ K,
                                                   const bf16* __restrict__ Vt_g,
                                                   const float* __restrict__ db,
                                                   bf16* __restrict__ xout) {
  const int tid = threadIdx.x;
  const int lane = tid & 63;
  const int w = tid >> 6;
  const int quad = lane >> 4;
  const int l15 = lane & 15;
  const int bh = blockIdx.x;          // b*16 + h
  const int h = bh & 15;
  const int b = bh >> 4;
  const int q0 = blockIdx.y * 128;

  __shared__ char smem[36864];
  bf16 (*Ks)[72] = (bf16(*)[72])smem;                    // [64 kv][72]
  bf16 (*Vt)[72] = (bf16(*)[72])(smem + 9216);           // [64 d][72] (kv cols)
  bf16 (*Pq)[72] = (bf16(*)[72])(smem + 18432 + w * 4608);  // per-wave [32 q][72]

  const size_t base = (size_t)bh * T_ * D_;
  const bf16* Qp = Q + base;
  const bf16* Kp = K + base;
  const bf16* Vp = Vt_g + base;       // [d][t]
  const float* dbh = db + h * NREL;

  const int qw = q0 + w * 32;
  // Q frags (serve as B-operand of S^T = K Q^T): Q[q=l15][d=ks*32+quad*8+j]
  bhalf8 aq[2][2];
#pragma unroll
  for (int qt = 0; qt < 2; ++qt)
#pragma unroll
    for (int ks = 0; ks < 2; ++ks)
      aq[qt][ks] = *(const bhalf8*)(Qp + (size_t)(qw + qt * 16 + l15) * D_ + ks * 32 + quad * 8);

  const f32x4 zero4 = {0.f, 0.f, 0.f, 0.f};
  f32x4 o[4][2];                      // O^T tiles [dt][qt]
#pragma unroll
  for (int dt = 0; dt < 4; ++dt)
#pragma unroll
    for (int qt = 0; qt < 2; ++qt) o[dt][qt] = zero4;
  float lsum[2] = {0.f, 0.f};

  for (int it = 0; it < 16; ++it) {
    const int kb = it * 64;
    __syncthreads();
    // stage K [kv][d] and V^T [d][kv]; both plain b128 (V already transposed)
#pragma unroll
    for (int s = 0; s < 2; ++s) {
      const int idx = tid + s * 256;
      const int row = idx >> 3;
      const int c8 = (idx & 7) * 8;
      *(bhalf8*)&Ks[row][c8] = *(const bhalf8*)(Kp + (size_t)(kb + row) * D_ + c8);
      *(bhalf8*)&Vt[row][c8] = *(const bhalf8*)(Vp + (size_t)row * T_ + kb + c8);
    }
    __syncthreads();

    // S^T = K Q^T: rows kv (4 tiles), cols q (2 tiles), K-dim d (2 steps)
    f32x4 st[4][2];
#pragma unroll
    for (int kvt = 0; kvt < 4; ++kvt) {
      const bhalf8 ak0 = *(const bhalf8*)&Ks[kvt * 16 + l15][quad * 8];
      const bhalf8 ak1 = *(const bhalf8*)&Ks[kvt * 16 + l15][32 + quad * 8];
#pragma unroll
      for (int qt = 0; qt < 2; ++qt) {
        f32x4 a = zero4;
        a = __builtin_amdgcn_mfma_f32_16x16x32_bf16(ak0, aq[qt][0], a, 0, 0, 0);
        a = __builtin_amdgcn_mfma_f32_16x16x32_bf16(ak1, aq[qt][1], a, 0, 0, 0);
        st[kvt][qt] = a;
      }
    }

    // p = exp2(s*scale' + bias'); partial l; pack 4 kv-consecutive -> b64 LDS
#pragma unroll
    for (int qt = 0; qt < 2; ++qt) {
      const int qg = qw + qt * 16 + l15;
#pragma unroll
      for (int kvt = 0; kvt < 4; ++kvt) {
        const int relb = qg - (kb + kvt * 16 + quad * 4) + 1023;
        bf16 t4[4];
#pragma unroll
        for (int rr = 0; rr < 4; ++rr) {
          const float p = exp2f(st[kvt][qt][rr] * 0.18033688011112f + dbh[relb - rr]);
          lsum[qt] += p;
          t4[rr] = __float2bfloat16(p);
        }
        *(uint2*)&Pq[qt * 16 + l15][kvt * 16 + quad * 4] = *(const uint2*)t4;
      }
    }

    // O^T += V^T P^T  (A-frag: Vt rows=d; B-frag: Pq rows=q, kv-contiguous)
#pragma unroll
    for (int ks = 0; ks < 2; ++ks) {
      bhalf8 pb[2];
#pragma unroll
      for (int qt = 0; qt < 2; ++qt)
        pb[qt] = *(const bhalf8*)&Pq[qt * 16 + l15][ks * 32 + quad * 8];
#pragma unroll
      for (int dt = 0; dt < 4; ++dt) {
        const bhalf8 av = *(const bhalf8*)&Vt[dt * 16 + l15][ks * 32 + quad * 8];
#pragma unroll
        for (int qt = 0; qt < 2; ++qt)
          o[dt][qt] = __builtin_amdgcn_mfma_f32_16x16x32_bf16(av, pb[qt], o[dt][qt], 0, 0, 0);
      }
    }
  }

  // deferred l-reduction over the 4 quads (lanes +-16, +-32)
  float rdiv[2];
#pragma unroll
  for (int qt = 0; qt < 2; ++qt) {
    float l = lsum[qt];
    l += __shfl_xor(l, 16, 64);
    l += __shfl_xor(l, 32, 64);
    rdiv[qt] = 1.0f / l;
  }

  // transpose O^T -> natural [q][d] via reused LDS, store coalesced to [B,T,E]
  __syncthreads();  // all waves done with Ks/Vt
  bf16 (*Ol)[72] = (bf16(*)[72])(smem + w * 4608);  // per-wave [32 q][72]
#pragma unroll
  for (int dt = 0; dt < 4; ++dt)
#pragma unroll
    for (int qt = 0; qt < 2; ++qt) {
      bf16 t4[4];
#pragma unroll
      for (int rr = 0; rr < 4; ++rr)
        t4[rr] = __float2bfloat16(o[dt][qt][rr] * rdiv[qt]);
      *(uint2*)&Ol[qt * 16 + l15][dt * 16 + quad * 4] = *(const uint2*)t4;
    }
  // wave-local RAW: compiler inserts lgkm wait
  const int row = lane >> 1;
  const int ch = (lane & 1) * 32;
  bf16* op = xout + ((size_t)b * T_ + qw + row) * E_ + h * 64 + ch;
#pragma unroll
  for (int c = 0; c < 4; ++c)
    *(bhalf8*)(op + c * 8) = *(const bhalf8*)&Ol[row][ch + c * 8];
}

// ---------------------------------------------------------------------------
extern "C" void kernel_launch(void* const* d_in, const int* in_sizes, int n_in,
                              void* d_out, int out_size, void* d_ws, size_t ws_size,
                              hipStream_t stream) {
  const float* query = (const float*)d_in[0];
  const float* key_  = (const float*)d_in[1];
  const float* value = (const float*)d_in[2];
  const float* Wq = (const float*)d_in[3];
  const float* bq = (const float*)d_in[4];
  const float* Wk = (const float*)d_in[5];
  const float* bk = (const float*)d_in[6];
  const float* Wv = (const float*)d_in[7];
  const float* bv = (const float*)d_in[8];
  const float* Wo = (const float*)d_in[9];
  const float* bo = (const float*)d_in[10];
  const float* table = (const float*)d_in[11];
  const float* offset = (const float*)d_in[12];
  float* out = (float*)d_out;

  char* ws = (char*)d_ws;
  const size_t ME = (size_t)B_ * T_ * E_;   // 8.4M elems
  const size_t EE = (size_t)E_ * E_;        // 1M elems
  float* db = (float*)ws;                   // 131008 B -> 131072
  bf16* wc  = (bf16*)(ws + 131072);         // Wq..Wo bf16, 4 x 2 MB
  bf16* qb  = wc + 4 * EE;                  // [B,H,T,D]
  bf16* kb  = qb + ME;                      // [B,H,T,D]
  bf16* vt  = kb + ME;                      // [B,H,D,T]  (pre-transposed)
  bf16* x2  = vt + ME;                      // attn out [B,T,E]

  dim3 bb(256, 1, 1);
  const int gEE = (int)(EE / 8 / 256);

  bias_pre<<<dim3(128), bb, 0, stream>>>(table, offset, db);
  cvt_f32_bf16<<<dim3(gEE), bb, 0, stream>>>(Wq, wc + 0 * EE, (int)EE);
  cvt_f32_bf16<<<dim3(gEE), bb, 0, stream>>>(Wk, wc + 1 * EE, (int)EE);
  cvt_f32_bf16<<<dim3(gEE), bb, 0, stream>>>(Wv, wc + 2 * EE, (int)EE);
  cvt_f32_bf16<<<dim3(gEE), bb, 0, stream>>>(Wo, wc + 3 * EE, (int)EE);

  // Q,K projections: A = fp32 activations (fused cvt), W-side = bf16 weights
  gemm_bt<1, 1, 0><<<dim3(64, 8), bb, 0, stream>>>(query, wc + 0 * EE, bq, qb);
  gemm_bt<1, 1, 0><<<dim3(64, 8), bb, 0, stream>>>(key_, wc + 1 * EE, bk, kb);
  // V projection, transposed output: rows = Wv out-features, cols = samples
  gemm_bt<2, 0, 1><<<dim3(8, 64), bb, 0, stream>>>(wc + 2 * EE, value, bv, vt);

  attn_kernel<<<dim3(128, 8), bb, 0, stream>>>(qb, kb, vt, db, x2);

  // output projection: A = x2 bf16, fp32 out
  gemm_bt<0, 0, 0><<<dim3(64, 8), bb, 0, stream>>>(x2, wc + 3 * EE, bo, out);
}